// Round 8
// baseline (358.759 us; speedup 1.0000x reference)
//
#include <hip/hip_runtime.h>
#include <hip/hip_bf16.h>

typedef __attribute__((ext_vector_type(8))) short bf16x8;
typedef __attribute__((ext_vector_type(4))) float f32x4;

#define MFMA_16x16x32(a,b,c) __builtin_amdgcn_mfma_f32_16x16x32_bf16((a),(b),(c),0,0,0)

__device__ __forceinline__ unsigned short f2b(float f){
  unsigned int u = __builtin_bit_cast(unsigned int, f);
  u = u + 0x7FFFu + ((u >> 16) & 1u);
  return (unsigned short)(u >> 16);
}
__device__ __forceinline__ float b2f(unsigned short h){
  unsigned int u = ((unsigned int)h) << 16;
  return __builtin_bit_cast(float, u);
}

__device__ __forceinline__ void gload_lds16(const unsigned short* g, unsigned short* l){
  __builtin_amdgcn_global_load_lds(
      (const __attribute__((address_space(1))) void*)g,
      (__attribute__((address_space(3))) void*)l, 16, 0, 0);
}

// ---------------- fused converters ----------------

__global__ void cvt_all(const float* __restrict__ hid, const float* __restrict__ wq,
                        const float* __restrict__ wk, const float* __restrict__ wv,
                        const float* __restrict__ wo,
                        unsigned short* __restrict__ Xb, unsigned short* __restrict__ Wqkv,
                        unsigned short* __restrict__ Wob){
  const int N0 = 2097152, N1 = 524288, N2 = 262144, N3 = 262144, N4 = 1048576;
  const int E1 = N0 + N1, E2 = E1 + N2, E3 = E2 + N3, E4 = E3 + N4;
  int i = blockIdx.x * blockDim.x + threadIdx.x;
  const int stride = gridDim.x * blockDim.x;
  for (; i < E4; i += stride){
    const float* s; unsigned short* d; int off;
    if (i < N0)      { s = hid; d = Xb;   off = i; }
    else if (i < E1) { s = wq;  d = Wqkv; off = i - N0; }
    else if (i < E2) { s = wk;  d = Wqkv; off = i - E1 + 524288; }
    else if (i < E3) { s = wv;  d = Wqkv; off = i - E2 + 786432; }
    else             { s = wo;  d = Wob;  off = i - E3; }
    int src_off = (i < N0) ? i : (i < E1) ? (i - N0) : (i < E2) ? (i - E1) : (i < E3) ? (i - E2) : (i - E3);
    float4 v = reinterpret_cast<const float4*>(s)[src_off];
    ushort4 o;
    o.x = f2b(v.x); o.y = f2b(v.y); o.z = f2b(v.z); o.w = f2b(v.w);
    reinterpret_cast<ushort4*>(d)[off] = o;
  }
}

__global__ void cvt_factors(const float* __restrict__ Bq, const float* __restrict__ Bk,
                            const float* __restrict__ Bv,
                            unsigned short* __restrict__ Bqt, unsigned short* __restrict__ Bkt,
                            unsigned short* __restrict__ Bvt){
  int i = blockIdx.x * blockDim.x + threadIdx.x;   // 32*8192
  if (i >= 32*8192) return;
  int H = i >> 13, e = i & 8191;
  int d = e & 127, r = (e >> 7) & 63;
  const float* src; unsigned short* dst; int h;
  if (H < 16)      { src = Bq; dst = Bqt; h = H; }
  else if (H < 24) { src = Bk; dst = Bkt; h = H - 16; }
  else             { src = Bv; dst = Bvt; h = H - 24; }
  dst[(h << 13) + (d << 6) + r] = f2b(src[(size_t)(h << 13) + e]);
}

// ---------------- big GEMM-BT ----------------

template<int OUT_F32>
__global__ __launch_bounds__(256) void gemm_bt(
    const unsigned short* __restrict__ A, const unsigned short* __restrict__ B,
    void* __restrict__ Cv, int N, int K, float scale)
{
  __shared__ unsigned short As[2][128*64];
  __shared__ unsigned short Bs[2][128*64];
  const int tid = threadIdx.x;
  const int mb = blockIdx.x, nb = blockIdx.y;
  const int w = tid >> 6, lane = tid & 63;
  const int wr = w >> 1, wc = w & 1;
  const int l16 = lane & 15, lg = lane >> 4;

  f32x4 acc[4][4] = {};

  const unsigned short* Ap = A + (size_t)(mb*128)*K;
  const unsigned short* Bp = B + (size_t)(nb*128)*K;

  const int sRo = 32*w + (lane >> 3);
  const int sCo = ((lane & 7) ^ (lane >> 3)) << 3;
  const int ldsW = 2048*w;

  auto stage = [&](int kt, int buf){
    const unsigned short* Ak = Ap + (size_t)kt*64 + sCo;
    const unsigned short* Bk = Bp + (size_t)kt*64 + sCo;
    #pragma unroll
    for (int i = 0; i < 4; i++)
      gload_lds16(Ak + (size_t)(sRo + 8*i)*K, &As[buf][ldsW + 512*i]);
    #pragma unroll
    for (int i = 0; i < 4; i++)
      gload_lds16(Bk + (size_t)(sRo + 8*i)*K, &Bs[buf][ldsW + 512*i]);
  };

  const int nkt = K >> 6;
  stage(0, 0);
  __syncthreads();

  int cur = 0;
  for (int kt = 0; kt < nkt; kt++){
    if (kt + 1 < nkt) stage(kt + 1, cur ^ 1);
    #pragma unroll
    for (int t = 0; t < 2; t++){
      bf16x8 af[4], bf[4];
      #pragma unroll
      for (int i = 0; i < 4; i++){
        int rowA = wr*64 + i*16 + l16;
        int col  = t*32 + lg*8;
        af[i] = *reinterpret_cast<const bf16x8*>(&As[cur][(rowA*64 + col) ^ ((rowA & 7) << 3)]);
        int rowB = wc*64 + i*16 + l16;
        bf[i] = *reinterpret_cast<const bf16x8*>(&Bs[cur][(rowB*64 + col) ^ ((rowB & 7) << 3)]);
      }
      #pragma unroll
      for (int i = 0; i < 4; i++)
        #pragma unroll
        for (int j = 0; j < 4; j++)
          acc[i][j] = MFMA_16x16x32(af[i], bf[j], acc[i][j]);
    }
    __syncthreads();
    cur ^= 1;
  }

  #pragma unroll
  for (int i = 0; i < 4; i++){
    #pragma unroll
    for (int j = 0; j < 4; j++){
      int row = mb*128 + wr*64 + i*16 + lg*4;
      int col = nb*128 + wc*64 + j*16 + l16;
      #pragma unroll
      for (int r = 0; r < 4; r++){
        float v = acc[i][j][r] * scale;
        if (OUT_F32) reinterpret_cast<float*>(Cv)[(size_t)(row + r)*N + col] = v;
        else reinterpret_cast<unsigned short*>(Cv)[(size_t)(row + r)*N + col] = f2b(v);
      }
    }
  }
}

// ---------------- fused factor GEMM + RoPE ----------------

__global__ __launch_bounds__(256) void factor_rope(
    const unsigned short* __restrict__ A,
    const unsigned short* __restrict__ Bqt, const unsigned short* __restrict__ Bkt,
    const unsigned short* __restrict__ Bvt,
    unsigned short* __restrict__ qb, unsigned short* __restrict__ kb2,
    unsigned short* __restrict__ vb,
    const float* __restrict__ fc, const float* __restrict__ fs)
{
  __shared__ unsigned short As[128*64];
  __shared__ unsigned short Bs[128*64];
  const int tid = threadIdx.x, mb = blockIdx.x, H = blockIdx.y;
  const int w = tid >> 6, lane = tid & 63;
  const int l16 = lane & 15, lg = lane >> 4;
  const float SCALE = 0.08838834764831845f;            // 128^-0.5
  const float LOG2E = 1.4426950408889634f;             // fold exp->exp2 into q

  int h, coloff, Hn; const unsigned short* Bt; unsigned short* Out; float scale; bool rope;
  if (H < 16)      { h = H;      coloff = h*64;        Hn = 16; Bt = Bqt + (size_t)h*8192; Out = qb;  scale = SCALE*LOG2E/64.f; rope = true; }
  else if (H < 24) { h = H - 16; coloff = 1024 + h*64; Hn = 8;  Bt = Bkt + (size_t)h*8192; Out = kb2; scale = 1.f/64.f;         rope = true; }
  else             { h = H - 24; coloff = 1536 + h*64; Hn = 8;  Bt = Bvt + (size_t)h*8192; Out = vb;  scale = 1.f/64.f;         rope = false; }

  const int srow = tid >> 3;
  const int scol = (tid & 7) << 3;
  const unsigned short* Ap = A + (size_t)(mb*128)*2048 + coloff;

  #pragma unroll
  for (int c = 0; c < 4; c++){
    int r = srow + 32*c;
    int idx = (r*64 + scol) ^ ((r & 7) << 3);
    *reinterpret_cast<bf16x8*>(&As[idx]) = *reinterpret_cast<const bf16x8*>(Ap + (size_t)r*2048 + scol);
    *reinterpret_cast<bf16x8*>(&Bs[idx]) = *reinterpret_cast<const bf16x8*>(Bt + r*64 + scol);
  }
  __syncthreads();

  f32x4 acc[2][8] = {};
  #pragma unroll
  for (int t = 0; t < 2; t++){
    bf16x8 af[2], bf[8];
    #pragma unroll
    for (int i = 0; i < 2; i++){
      int rowA = w*32 + i*16 + l16;
      int col  = t*32 + lg*8;
      af[i] = *reinterpret_cast<const bf16x8*>(&As[(rowA*64 + col) ^ ((rowA & 7) << 3)]);
    }
    #pragma unroll
    for (int j = 0; j < 8; j++){
      int rowB = j*16 + l16;
      int col  = t*32 + lg*8;
      bf[j] = *reinterpret_cast<const bf16x8*>(&Bs[(rowB*64 + col) ^ ((rowB & 7) << 3)]);
    }
    #pragma unroll
    for (int i = 0; i < 2; i++)
      #pragma unroll
      for (int j = 0; j < 8; j++)
        acc[i][j] = MFMA_16x16x32(af[i], bf[j], acc[i][j]);
  }

  #pragma unroll
  for (int i = 0; i < 2; i++){
    #pragma unroll
    for (int j = 0; j < 4; j++){
      int d = j*16 + l16;
      #pragma unroll
      for (int r = 0; r < 4; r++){
        int row = mb*128 + w*32 + i*16 + lg*4 + r;
        int s = row & 2047, bb = row >> 11;
        float lo = acc[i][j][r] * scale;
        float hi = acc[i][j+4][r] * scale;
        float o1, o2;
        if (rope){
          float cc = fc[(size_t)s*64 + d];
          float ss = fs[(size_t)s*64 + d];
          o1 = lo*cc - hi*ss;
          o2 = lo*ss + hi*cc;
        } else { o1 = lo; o2 = hi; }
        size_t base = ((size_t)(bb*Hn + h)*2048 + s)*128;
        Out[base + d]      = f2b(o1);
        Out[base + 64 + d] = f2b(o2);
      }
    }
  }
}

// ---------------- flash attention: swapped-MFMA (lane-owns-q-row), early-stage overlap ----------------
// S^T = mfma(K,Q): lane (l16,lg) holds S[k = kb*64 + nt*16 + lg*4 + r][q = l16-row].
// Softmax per lane: in-register tree + 2 shfl_xor (lg halves). P -> Pl[q][k^swz] -> PV B-frag b128.
// PV: O^T = mfma(V^T, P^T): oac[dn] reg r = O[q=l16][d = dn*16 + lg*4 + r].
// Barrier B' placed right after QK reads; stage(next) issued there -> overlaps softmax+Pl+PV.

__device__ __forceinline__ int vt_idx(int d, int kv){
  return d*64 + ((((kv >> 3) + d + (d >> 3)) & 7) << 3) + (kv & 7);
}

__global__ __launch_bounds__(256) void flash_attn(
    const unsigned short* __restrict__ Q,   // (B,16,2048,128) roped, pre-scaled by SCALE*log2e/RQ
    const unsigned short* __restrict__ Kb,  // (B,8,2048,128) roped, /RK
    const unsigned short* __restrict__ Vb,  // (B,8,2048,128) /RV
    unsigned short* __restrict__ O)         // (B*2048, 2048)
{
  __shared__ unsigned short Ks[64*128];
  __shared__ unsigned short Vrow[64*128];
  __shared__ unsigned short Vt[128*64];
  __shared__ unsigned short Pl[4][16*64];

  const int tid = threadIdx.x;
  const int w = tid >> 6, lane = tid & 63;
  const int l16 = lane & 15, lg = lane >> 4;
  const int h = blockIdx.y, b = blockIdx.z;
  const int hkv = h >> 1;

  const size_t hbase  = ((size_t)(b*16 + h))*2048*128;
  const size_t kvbase = ((size_t)(b*8 + hkv))*2048*128;

  const int sR = w*16 + (lane >> 4);
  const int sC = (lane & 15) * 8;

  auto stage = [&](int kb){
    #pragma unroll
    for (int i = 0; i < 4; i++){
      int R = sR + i*4;
      const unsigned short* gk = Kb + kvbase + (size_t)(kb*64 + R)*128 + (sC ^ ((R & 7) << 3));
      gload_lds16(gk, &Ks[(w*16 + i*4)*128]);
      const unsigned short* gv = Vb + kvbase + (size_t)(kb*64 + R)*128 + sC;
      gload_lds16(gv, &Vrow[(w*16 + i*4)*128]);
    }
  };

  stage(0);
  __syncthreads();

  const int tkv0 = (tid >> 4) * 4;
  const int td0  = (tid & 15) * 8;

  const int qtiles[2] = { (int)blockIdx.x, 31 - (int)blockIdx.x };

  for (int ph = 0; ph < 2; ph++){
    const int qe = qtiles[ph];
    const size_t qbase = hbase + (size_t)(qe*64 + w*16)*128;
    const int qrow = qe*64 + w*16 + l16;    // this lane's q-row

    bf16x8 aq[4];
    #pragma unroll
    for (int t = 0; t < 4; t++)
      aq[t] = *reinterpret_cast<const bf16x8*>(&Q[qbase + (size_t)l16*128 + t*32 + lg*8]);

    f32x4 oac[8] = {};
    float mreg = -1e30f, lreg = 0.f;

    for (int kb = 0; kb <= qe; kb++){
      bf16x8 vr0 = *reinterpret_cast<const bf16x8*>(&Vrow[(tkv0 + 0)*128 + td0]);
      bf16x8 vr1 = *reinterpret_cast<const bf16x8*>(&Vrow[(tkv0 + 1)*128 + td0]);
      bf16x8 vr2 = *reinterpret_cast<const bf16x8*>(&Vrow[(tkv0 + 2)*128 + td0]);
      bf16x8 vr3 = *reinterpret_cast<const bf16x8*>(&Vrow[(tkv0 + 3)*128 + td0]);

      // S^T: lane holds 16 k-values for q-row l16
      f32x4 sac[4] = {};
      #pragma unroll
      for (int nt = 0; nt < 4; nt++){
        #pragma unroll
        for (int t = 0; t < 4; t++){
          int rowK = nt*16 + l16;
          int col  = t*32 + lg*8;
          bf16x8 bk = *reinterpret_cast<const bf16x8*>(&Ks[(rowK*128 + col) ^ ((rowK & 7) << 3)]);
          sac[nt] = MFMA_16x16x32(bk, aq[t], sac[nt]);   // swapped: K as A, Q as B
        }
      }

      // transposed V for PV
      #pragma unroll
      for (int j = 0; j < 8; j++){
        unsigned int lo = (unsigned int)(unsigned short)vr0[j] | ((unsigned int)(unsigned short)vr1[j] << 16);
        unsigned int hi = (unsigned int)(unsigned short)vr2[j] | ((unsigned int)(unsigned short)vr3[j] << 16);
        uint2 u; u.x = lo; u.y = hi;
        *reinterpret_cast<uint2*>(&Vt[vt_idx(td0 + j, tkv0)]) = u;
      }

      if (kb == qe){
        #pragma unroll
        for (int nt = 0; nt < 4; nt++){
          int k0 = kb*64 + nt*16 + lg*4;
          #pragma unroll
          for (int r = 0; r < 4; r++)
            if (k0 + r > qrow) sac[nt][r] = -1e30f;
        }
      }

      __syncthreads();                 // B': Ks/Vrow reads done, Vt visible
      if (kb < qe) stage(kb + 1);      // overlaps softmax + Pl + PV
      else if (ph == 0) stage(0);

      // --- in-lane softmax (log2 domain) ---
      float pm0 = fmaxf(fmaxf(sac[0][0], sac[0][1]), fmaxf(sac[0][2], sac[0][3]));
      float pm1 = fmaxf(fmaxf(sac[1][0], sac[1][1]), fmaxf(sac[1][2], sac[1][3]));
      float pm2 = fmaxf(fmaxf(sac[2][0], sac[2][1]), fmaxf(sac[2][2], sac[2][3]));
      float pm3 = fmaxf(fmaxf(sac[3][0], sac[3][1]), fmaxf(sac[3][2], sac[3][3]));
      float v = fmaxf(fmaxf(pm0, pm1), fmaxf(pm2, pm3));
      v = fmaxf(v, __shfl_xor(v, 16));
      v = fmaxf(v, __shfl_xor(v, 32));
      float mn = fmaxf(mreg, v);
      float corr = exp2f(mreg - mn);
      mreg = mn;
      float rs = 0.f;
      #pragma unroll
      for (int nt = 0; nt < 4; nt++){
        #pragma unroll
        for (int r = 0; r < 4; r++){
          float pp = exp2f(sac[nt][r] - mn);
          sac[nt][r] = pp;
          rs += pp;
        }
      }
      rs += __shfl_xor(rs, 16);
      rs += __shfl_xor(rs, 32);
      lreg = lreg*corr + rs;
      #pragma unroll
      for (int dn = 0; dn < 8; dn++)
        #pragma unroll
        for (int r = 0; r < 4; r++) oac[dn][r] *= corr;

      // P^T -> Pl[q][k ^ ((q&7)<<3)]
      #pragma unroll
      for (int nt = 0; nt < 4; nt++){
        #pragma unroll
        for (int r = 0; r < 4; r++){
          int k = nt*16 + lg*4 + r;
          Pl[w][l16*64 + (k ^ ((l16 & 7) << 3))] = f2b(sac[nt][r]);
        }
      }
      asm volatile("s_waitcnt lgkmcnt(0)" ::: "memory");
      __builtin_amdgcn_sched_barrier(0);

      // PV: O^T += V^T * P^T
      #pragma unroll
      for (int t = 0; t < 2; t++){
        bf16x8 ap = *reinterpret_cast<const bf16x8*>(&Pl[w][l16*64 + ((t*32 + lg*8) ^ ((l16 & 7) << 3))]);
        #pragma unroll
        for (int dn = 0; dn < 8; dn++){
          int rowV = dn*16 + l16;
          bf16x8 bv = *reinterpret_cast<const bf16x8*>(&Vt[vt_idx(rowV, t*32 + lg*8)]);
          oac[dn] = MFMA_16x16x32(bv, ap, oac[dn]);      // swapped: V^T as A, P^T as B
        }
      }
      __syncthreads();                 // A: drains stage (long overlap window)
    }

    // epilogue: lane owns q-row `qrow`; oac[dn] reg r = O[qrow][dn*16 + lg*4 + r]
    float inv = 1.0f / lreg;
    #pragma unroll
    for (int dn = 0; dn < 8; dn++){
      ushort4 o;
      o.x = f2b(oac[dn][0] * inv);
      o.y = f2b(oac[dn][1] * inv);
      o.z = f2b(oac[dn][2] * inv);
      o.w = f2b(oac[dn][3] * inv);
      *reinterpret_cast<ushort4*>(&O[((size_t)(b*2048 + qrow))*2048 + h*128 + dn*16 + lg*4]) = o;
    }
  }
}

// ---------------- launcher ----------------

extern "C" void kernel_launch(void* const* d_in, const int* in_sizes, int n_in,
                              void* d_out, int out_size, void* d_ws, size_t ws_size,
                              hipStream_t stream)
{
  if (n_in < 10) return;
  const float* hidden = (const float*)d_in[0];
  const float* WAq = (const float*)d_in[1];
  const float* WAk = (const float*)d_in[2];
  const float* WAv = (const float*)d_in[3];
  const float* Bq  = (const float*)d_in[4];
  const float* Bk  = (const float*)d_in[5];
  const float* Bv  = (const float*)d_in[6];
  const float* Wo  = (const float*)d_in[7];
  const float* fcos = (const float*)d_in[8];
  const float* fsin = (const float*)d_in[9];
  float* out = (float*)d_out;

  char* p = (char*)d_ws;
  auto take = [&](size_t bytes){ char* q = p; p += (bytes + 255) & ~(size_t)255; return q; };
  unsigned short* Xb   = (unsigned short*)take((size_t)4096*2048*2);
  unsigned short* Wqkv = (unsigned short*)take((size_t)2048*2048*2);
  unsigned short* Wob  = (unsigned short*)take((size_t)2048*2048*2);
  unsigned short* Aqkv = (unsigned short*)take((size_t)4096*2048*2);
  unsigned short* Bqt  = (unsigned short*)take((size_t)16*128*64*2);
  unsigned short* Bkt  = (unsigned short*)take((size_t)8*128*64*2);
  unsigned short* Bvt  = (unsigned short*)take((size_t)8*128*64*2);
  unsigned short* qbuf = (unsigned short*)take((size_t)2*16*2048*128*2);
  unsigned short* kbuf = (unsigned short*)take((size_t)2*8*2048*128*2);
  unsigned short* vbuf = (unsigned short*)take((size_t)2*8*2048*128*2);
  unsigned short* aout = (unsigned short*)take((size_t)4096*2048*2);
  if ((size_t)(p - (char*)d_ws) > ws_size) return;

  cvt_all<<<4096, 256, 0, stream>>>(hidden, WAq, WAk, WAv, Wo, Xb, Wqkv, Wob);
  cvt_factors<<<1024, 256, 0, stream>>>(Bq, Bk, Bv, Bqt, Bkt, Bvt);

  gemm_bt<0><<<dim3(32,16), 256, 0, stream>>>(Xb, Wqkv, (void*)Aqkv, 2048, 2048, 1.0f);

  factor_rope<<<dim3(32,32), 256, 0, stream>>>(Aqkv, Bqt, Bkt, Bvt, qbuf, kbuf, vbuf, fcos, fsin);

  flash_attn<<<dim3(16,16,2), 256, 0, stream>>>(qbuf, kbuf, vbuf, aout);

  gemm_bt<1><<<dim3(32,16), 256, 0, stream>>>(aout, Wob, (void*)out, 2048, 2048, 1.0f);
}